// Round 7
// baseline (353.841 us; speedup 1.0000x reference)
//
#include <hip/hip_runtime.h>
#include <hip/hip_bf16.h>
#include <stdint.h>

// QSCrossAttention: B=8, Nq=1024, Nkv=4096, D=512, fp32 I/O, bf16 MFMA compute.
// R7: occupancy round. R6 showed S at Occ 18%, Mfma 9.5%, BW 15% — pure
//     latency. gemm_bt: Rt repack shrunk to 64 rows (17.4KB LDS) + 2-phase
//     store + __launch_bounds__(256,4) -> 4 blk/CU. pv: 32-row q-tiles,
//     grid 1024, 4 blk/CU.

typedef __bf16 bf16;
typedef bf16 bf16x8 __attribute__((ext_vector_type(8)));
typedef bf16 bf16x4 __attribute__((ext_vector_type(4)));
typedef float f32x4 __attribute__((ext_vector_type(4)));

#define NB 8
#define NQ 1024
#define NKV 4096
#define DD 512
#define RT_LD 136  // repack leading dim (bf16)

__device__ __forceinline__ void direct16(const void* g, void* s) {
  __builtin_amdgcn_global_load_lds(
      (const __attribute__((address_space(1))) void*)g,
      (__attribute__((address_space(3))) void*)s, 16, 0, 0);
}

__global__ void cvt_kernel(const float* __restrict__ src, bf16* __restrict__ dst, int n4) {
  int i = blockIdx.x * blockDim.x + threadIdx.x;
  if (i < n4) {
    float4 v = ((const float4*)src)[i];
    bf16x4 o;
    o.x = (bf16)v.x; o.y = (bf16)v.y; o.z = (bf16)v.z; o.w = (bf16)v.w;
    ((bf16x4*)dst)[i] = o;
  }
}

__global__ void cvt_weights(const float* __restrict__ Wq, const float* __restrict__ Wk,
                            const float* __restrict__ Wv, const float* __restrict__ Wp,
                            bf16* __restrict__ Wq_b, bf16* __restrict__ Wkv_b,
                            bf16* __restrict__ Wp_b) {
  int i = blockIdx.x * blockDim.x + threadIdx.x;
  int w = i >> 16, r = i & 65535;
  const float* src = (w == 0) ? Wq : (w == 1) ? Wk : (w == 2) ? Wv : Wp;
  bf16x4* dst = (w == 0) ? (bf16x4*)Wq_b
              : (w == 3) ? (bf16x4*)Wp_b
                         : (bf16x4*)Wkv_b + (w == 2 ? 65536 : 0);
  float4 v = ((const float4*)src)[r];
  bf16x4 o;
  o.x = (bf16)v.x; o.y = (bf16)v.y; o.z = (bf16)v.z; o.w = (bf16)v.w;
  dst[r] = o;
}

__global__ void sniff_zero(const unsigned* __restrict__ mask, int* __restrict__ flag,
                           float* __restrict__ denom) {
  __shared__ int s_bad0, s_bad1;
  if (threadIdx.x == 0) { s_bad0 = 0; s_bad1 = 0; }
  __syncthreads();
  int b0 = 0, b1 = 0;
  for (int i = threadIdx.x; i < 8192; i += 256) {
    unsigned v = mask[i];
    if (v > 1u) b0 = 1;
    if (v != 0u && v != 0x3F800000u) b1 = 1;
  }
  if (b0) atomicOr(&s_bad0, 1);
  if (b1) atomicOr(&s_bad1, 1);
  for (int i = threadIdx.x; i < NB * NQ; i += 256) denom[i] = 0.f;
  __syncthreads();
  if (threadIdx.x == 0) *flag = (s_bad0 == 0) ? 0 : ((s_bad1 == 0) ? 1 : 2);
}

__global__ void scan_mask(const void* __restrict__ mask, const int* __restrict__ flagP,
                          int* __restrict__ idx, int* __restrict__ cnt,
                          int* __restrict__ kpad) {
  const int b = blockIdx.x, tid = threadIdx.x;
  const int mode = *flagP;
  __shared__ int ps[256];
  unsigned bits = 0;
  int c = 0;
  const int base = tid * 16;
  for (int i = 0; i < 16; ++i) {
    const int col = base + i;
    bool k;
    if (mode == 0)      k = ((const int*)mask)[b * NKV + col] != 0;
    else if (mode == 1) k = ((const float*)mask)[b * NKV + col] != 0.f;
    else                k = ((const unsigned char*)mask)[b * NKV + col] != 0;
    bits |= (unsigned)k << i;
    c += k;
  }
  ps[tid] = c;
  __syncthreads();
  for (int s = 1; s < 256; s <<= 1) {
    int v = (tid >= s) ? ps[tid - s] : 0;
    __syncthreads();
    ps[tid] += v;
    __syncthreads();
  }
  int off = ps[tid] - c;
  for (int i = 0; i < 16; ++i)
    if ((bits >> i) & 1) idx[b * NKV + off++] = base + i;
  if (tid == 255) {
    cnt[b] = ps[255];
    kpad[b] = (ps[255] + 127) & ~127;
  }
}

__global__ void gather_qx(const float* __restrict__ qx, const int* __restrict__ idx,
                          const int* __restrict__ cnt, bf16* __restrict__ qc) {
  const int b = blockIdx.y;
  const int wave = threadIdx.x >> 6, lane = threadIdx.x & 63;
  const int r0 = blockIdx.x * 16 + wave * 4;
  const int n = cnt[b];
#pragma unroll
  for (int j = 0; j < 4; ++j) {
    const int row = r0 + j;
    if (row >= n) return;
    const int src = idx[b * NKV + row];
    const float4* s = (const float4*)(qx + ((long)b * NKV + src) * DD) + lane;
    bf16x4* d = (bf16x4*)(qc + ((long)b * NKV + row) * DD) + lane;
    float4 v0 = s[0], v1 = s[64];
    bf16x4 o0, o1;
    o0.x = (bf16)v0.x; o0.y = (bf16)v0.y; o0.z = (bf16)v0.z; o0.w = (bf16)v0.w;
    o1.x = (bf16)v1.x; o1.y = (bf16)v1.y; o1.z = (bf16)v1.z; o1.w = (bf16)v1.w;
    d[0] = o0;
    d[64] = o1;
  }
}

// ---------------- 128x128-tile GEMM (S and kv projections) -----------------
// LDS = 17408B: As|Bs (16KB) in K-loop; 64-row Rt overlays for the 2-phase
// coalesced epilogue. 4 blocks/CU.
// EPI 2 = S: exp + col<cnt zeroing + rowsum + P store.
// EPI 5 = kv dual (k row-major | vT transposed).
template <int EPI>
__global__ void __launch_bounds__(256, 4)
gemm_bt(const bf16* __restrict__ A, const bf16* __restrict__ Bw,
        void* __restrict__ Cp, void* __restrict__ Cp2,
        int N, int Klen, int Kstride,
        long sA, long sB, long sC,
        const int* __restrict__ cnt, const int* __restrict__ kpad,
        float* __restrict__ denom, float scale, int M) {
  __shared__ alignas(16) bf16 Smem[64 * RT_LD];  // 17408 B
  bf16* As = Smem;
  bf16* Bs = Smem + 4096;
  bf16* Rt = Smem;
  const int tid = threadIdx.x;
  const int wave = tid >> 6, lane = tid & 63;
  const int l15 = lane & 15, l4 = lane >> 4;
  const int wm = (wave >> 1) * 64, wn = (wave & 1) * 64;
  const int bx = (EPI == 5) ? blockIdx.y : blockIdx.x;
  const int by = (EPI == 5) ? blockIdx.x : blockIdx.y;
  const int b = blockIdx.z;

  if constexpr (EPI == 2) {
    if (bx * 128 >= kpad[b]) return;
  } else {
    const int bb = by >> 5, loc = (by & 31) * 128;
    if (loc >= kpad[bb]) return;
  }

  const bf16* Ab = A + (long)b * sA + (long)(by * 128) * Kstride;
  const bf16* Bb = Bw + (long)b * sB + (long)(bx * 128) * Kstride;

  const int c0 = wave * 2, c1 = wave * 2 + 1;
  const int srow = lane >> 2;
  const int scol = (lane & 3) * 8;
  const bf16* ag0 = Ab + (long)(c0 * 16 + srow) * Kstride + scol;
  const bf16* ag1 = Ab + (long)(c1 * 16 + srow) * Kstride + scol;
  const bf16* bg0 = Bb + (long)(c0 * 16 + srow) * Kstride + scol;
  const bf16* bg1 = Bb + (long)(c1 * 16 + srow) * Kstride + scol;
  bf16* al0 = As + c0 * 512 + lane * 8;
  bf16* al1 = As + c1 * 512 + lane * 8;
  bf16* bl0 = Bs + c0 * 512 + lane * 8;
  bf16* bl1 = Bs + c1 * 512 + lane * 8;

  f32x4 acc[4][4] = {};

  for (int kt = 0; kt < Klen; kt += 32) {
    __syncthreads();
    direct16(ag0, al0);
    direct16(ag1, al1);
    direct16(bg0, bl0);
    direct16(bg1, bl1);
    ag0 += 32; ag1 += 32; bg0 += 32; bg1 += 32;
    __syncthreads();
    bf16x8 af[4], bfr[4];
#pragma unroll
    for (int t = 0; t < 4; ++t)
      af[t] = *(const bf16x8*)(As + (wm + t * 16 + l15) * 32 + l4 * 8);
#pragma unroll
    for (int t = 0; t < 4; ++t)
      bfr[t] = *(const bf16x8*)(Bs + (wn + t * 16 + l15) * 32 + l4 * 8);
#pragma unroll
    for (int mt = 0; mt < 4; ++mt)
#pragma unroll
      for (int nt = 0; nt < 4; ++nt)
        acc[mt][nt] = __builtin_amdgcn_mfma_f32_16x16x32_bf16(af[mt], bfr[nt],
                                                              acc[mt][nt], 0, 0, 0);
  }

  const int rowBase = by * 128 + wm;
  const int colBase = bx * 128 + wn;
  const int tR = by * 128;
  const int tC = bx * 128;

  __syncthreads();  // K-loop LDS readers done before Rt overlay

  if constexpr (EPI == 2) {
    bf16* C = (bf16*)Cp + (long)b * sC;
    const int nkeep = cnt[b];
#pragma unroll
    for (int h2 = 0; h2 < 2; ++h2) {
      if (wm == h2 * 64) {  // wave-uniform: owning wave-pair fills Rt
        float rs[4][4];
#pragma unroll
        for (int mt = 0; mt < 4; ++mt)
#pragma unroll
          for (int r = 0; r < 4; ++r) rs[mt][r] = 0.f;
#pragma unroll
        for (int nt = 0; nt < 4; ++nt) {
          const bool keep = (colBase + nt * 16 + l15) < nkeep;
#pragma unroll
          for (int mt = 0; mt < 4; ++mt)
#pragma unroll
            for (int r = 0; r < 4; ++r) {
              float p = keep ? __expf(acc[mt][nt][r] * scale) : 0.f;
              rs[mt][r] += p;
              Rt[(mt * 16 + l4 * 4 + r) * RT_LD + wn + nt * 16 + l15] = (bf16)p;
            }
        }
#pragma unroll
        for (int mt = 0; mt < 4; ++mt)
#pragma unroll
          for (int r = 0; r < 4; ++r) {
            float v = rs[mt][r];
            v += __shfl_xor(v, 1, 64);
            v += __shfl_xor(v, 2, 64);
            v += __shfl_xor(v, 4, 64);
            v += __shfl_xor(v, 8, 64);
            if (l15 == 0)
              atomicAdd(&denom[b * M + rowBase + mt * 16 + l4 * 4 + r], v);
          }
      }
      __syncthreads();
      const int r0 = tid >> 2, cq = (tid & 3) * 32;
#pragma unroll
      for (int j = 0; j < 4; ++j) {
        bf16x8 v = *(const bf16x8*)(Rt + r0 * RT_LD + cq + j * 8);
        *(bf16x8*)(C + (long)(tR + h2 * 64 + r0) * N + tC + cq + j * 8) = v;
      }
      __syncthreads();
    }
  } else {  // EPI == 5
    if (tC < 512) {
      bf16* C = (bf16*)Cp;  // k: [B*NKV][512]
#pragma unroll
      for (int h2 = 0; h2 < 2; ++h2) {
        if (wm == h2 * 64) {
#pragma unroll
          for (int mt = 0; mt < 4; ++mt)
#pragma unroll
            for (int nt = 0; nt < 4; ++nt)
#pragma unroll
              for (int r = 0; r < 4; ++r)
                Rt[(mt * 16 + l4 * 4 + r) * RT_LD + wn + nt * 16 + l15] =
                    (bf16)acc[mt][nt][r];
        }
        __syncthreads();
        const int r0 = tid >> 2, cq = (tid & 3) * 32;
#pragma unroll
        for (int j = 0; j < 4; ++j) {
          bf16x8 v = *(const bf16x8*)(Rt + r0 * RT_LD + cq + j * 8);
          *(bf16x8*)(C + (long)(tR + h2 * 64 + r0) * 512 + tC + cq + j * 8) = v;
        }
        __syncthreads();
      }
    } else {
      bf16* C = (bf16*)Cp2;  // vT: [B][512][NKV]; Rt[d-local 64][kv-local 128]
      const int bb = tR >> 12, kvloc = tR & 4095;
#pragma unroll
      for (int h2 = 0; h2 < 2; ++h2) {
        if (wn == h2 * 64) {  // wave-uniform: this wave-pair owns d-half h2
#pragma unroll
          for (int mt = 0; mt < 4; ++mt) {
            const int r0k = wm + mt * 16 + l4 * 4;  // kv-local row
#pragma unroll
            for (int nt = 0; nt < 4; ++nt) {
              const int dl = nt * 16 + l15;  // d-local within half
              bf16x4 o;
              o.x = (bf16)acc[mt][nt][0]; o.y = (bf16)acc[mt][nt][1];
              o.z = (bf16)acc[mt][nt][2]; o.w = (bf16)acc[mt][nt][3];
              *(bf16x4*)(Rt + dl * RT_LD + r0k) = o;
            }
          }
        }
        __syncthreads();
        const int d0 = tid >> 2, kvq = (tid & 3) * 32;
#pragma unroll
        for (int j = 0; j < 4; ++j) {
          bf16x8 v = *(const bf16x8*)(Rt + d0 * RT_LD + kvq + j * 8);
          *(bf16x8*)(C + (long)bb * DD * NKV +
                     (long)(tC - 512 + h2 * 64 + d0) * NKV + kvloc + kvq + j * 8) = v;
        }
        __syncthreads();
      }
    }
  }
}

// ---------------- 128x64-tile GEMM (q-proj, out-proj) ----------------------
template <int EPI>
__global__ void __launch_bounds__(256, 4)
gemm_n64(const bf16* __restrict__ A, const bf16* __restrict__ Bw,
         void* __restrict__ Cp) {
  constexpr int SME = (EPI == 0) ? 128 * 72 : 6144;
  __shared__ alignas(16) bf16 Smem[SME];
  bf16* As = Smem;
  bf16* Bs = Smem + 4096;
  bf16* Rt = Smem;
  const int tid = threadIdx.x;
  const int wave = tid >> 6, lane = tid & 63;
  const int l15 = lane & 15, l4 = lane >> 4;
  const int wm = (wave >> 1) * 64, wn = (wave & 1) * 32;

  const bf16* Ab = A + (long)(blockIdx.y * 128) * DD;
  const bf16* Bb = Bw + (long)(blockIdx.x * 64) * DD;

  const int srow = lane >> 2, scol = (lane & 3) * 8;
  const bf16* ag0 = Ab + (long)(wave * 32 + srow) * DD + scol;
  const bf16* ag1 = ag0 + 16 * DD;
  const bf16* bg0 = Bb + (long)(wave * 16 + srow) * DD + scol;
  bf16* al0 = As + wave * 1024 + lane * 8;
  bf16* al1 = al0 + 512;
  bf16* bl0 = Bs + wave * 512 + lane * 8;

  f32x4 acc[4][2] = {};

  for (int kt = 0; kt < DD; kt += 32) {
    __syncthreads();
    direct16(ag0, al0);
    direct16(ag1, al1);
    direct16(bg0, bl0);
    ag0 += 32; ag1 += 32; bg0 += 32;
    __syncthreads();
    bf16x8 af[4], bfr[2];
#pragma unroll
    for (int t = 0; t < 4; ++t)
      af[t] = *(const bf16x8*)(As + (wm + t * 16 + l15) * 32 + l4 * 8);
#pragma unroll
    for (int t = 0; t < 2; ++t)
      bfr[t] = *(const bf16x8*)(Bs + (wn + t * 16 + l15) * 32 + l4 * 8);
#pragma unroll
    for (int mt = 0; mt < 4; ++mt)
#pragma unroll
      for (int nt = 0; nt < 2; ++nt)
        acc[mt][nt] = __builtin_amdgcn_mfma_f32_16x16x32_bf16(af[mt], bfr[nt],
                                                              acc[mt][nt], 0, 0, 0);
  }

  const int tR = blockIdx.y * 128, tC = blockIdx.x * 64;
  if constexpr (EPI == 0) {
    __syncthreads();
#pragma unroll
    for (int mt = 0; mt < 4; ++mt)
#pragma unroll
      for (int nt = 0; nt < 2; ++nt)
#pragma unroll
        for (int r = 0; r < 4; ++r)
          Rt[(wm + mt * 16 + l4 * 4 + r) * 72 + wn + nt * 16 + l15] =
              (bf16)acc[mt][nt][r];
    __syncthreads();
    bf16* C = (bf16*)Cp;
    const int r0 = tid >> 1, cq = (tid & 1) * 32;
#pragma unroll
    for (int j = 0; j < 4; ++j) {
      bf16x8 v = *(const bf16x8*)(Rt + r0 * 72 + cq + j * 8);
      *(bf16x8*)(C + (long)(tR + r0) * DD + tC + cq + j * 8) = v;
    }
  } else {
    float* C = (float*)Cp;
#pragma unroll
    for (int mt = 0; mt < 4; ++mt)
#pragma unroll
      for (int nt = 0; nt < 2; ++nt)
#pragma unroll
        for (int r = 0; r < 4; ++r)
          C[(long)(tR + wm + mt * 16 + l4 * 4 + r) * DD + tC + wn + nt * 16 + l15] =
              acc[mt][nt][r];
  }
}

// ---------------- PV direct: x = (P @ vT^T) / denom ------------------------
// Tile 32q x 128d, K = kpad[b]. Grid (32,4,8) = 1024 blocks, 4 blk/CU.
// Waves: wm=(wave>>1)*16 (q), wn=(wave&1)*64 (d); acc[1][4].
__global__ void __launch_bounds__(256, 4)
pv_direct(const bf16* __restrict__ P, const bf16* __restrict__ vT,
          const float* __restrict__ denom, const int* __restrict__ kpad,
          bf16* __restrict__ x) {
  __shared__ alignas(16) bf16 Smem[5120];  // As 1024 + Bs 4096 elems; Rt 4352
  bf16* As = Smem;
  bf16* Bs = Smem + 1024;
  bf16* Rt = Smem;
  const int tid = threadIdx.x;
  const int wave = tid >> 6, lane = tid & 63;
  const int l15 = lane & 15, l4 = lane >> 4;
  const int wm = (wave >> 1) * 16, wn = (wave & 1) * 64;
  const int qB = blockIdx.x * 32;
  const int dB = blockIdx.y * 128;
  const int b = blockIdx.z;
  const int Kb = kpad[b];

  const bf16* Ab = P + (long)b * NQ * NKV + (long)qB * NKV;
  const bf16* Bb = vT + (long)b * DD * NKV + (long)dB * NKV;

  const int srow = lane >> 2, scol = (lane & 3) * 8;
  // A: 32 rows, 2 chunks staged by waves 0,1
  const bf16* ag = Ab + (long)(wave * 16 + srow) * NKV + scol;
  bf16* al = As + wave * 512 + lane * 8;
  // B: 128 rows, 8 chunks, 2 per wave
  const bf16* bg0 = Bb + (long)(wave * 32 + srow) * NKV + scol;
  const bf16* bg1 = bg0 + 16 * NKV;
  bf16* bl0 = Bs + wave * 1024 + lane * 8;
  bf16* bl1 = bl0 + 512;

  f32x4 acc[4] = {};

  for (int kt = 0; kt < Kb; kt += 32) {
    __syncthreads();
    if (wave < 2) direct16(ag, al);
    direct16(bg0, bl0);
    direct16(bg1, bl1);
    ag += 32; bg0 += 32; bg1 += 32;
    __syncthreads();
    bf16x8 af, bfr[4];
    af = *(const bf16x8*)(As + (wm + l15) * 32 + l4 * 8);
#pragma unroll
    for (int t = 0; t < 4; ++t)
      bfr[t] = *(const bf16x8*)(Bs + (wn + t * 16 + l15) * 32 + l4 * 8);
#pragma unroll
    for (int nt = 0; nt < 4; ++nt)
      acc[nt] = __builtin_amdgcn_mfma_f32_16x16x32_bf16(af, bfr[nt], acc[nt], 0, 0, 0);
  }

  __syncthreads();
#pragma unroll
  for (int r = 0; r < 4; ++r) {
    const int row = wm + l4 * 4 + r;
    const float inv = 1.0f / denom[b * NQ + qB + row];
#pragma unroll
    for (int nt = 0; nt < 4; ++nt)
      Rt[row * RT_LD + wn + nt * 16 + l15] = (bf16)(acc[nt][r] * inv);
  }
  __syncthreads();
  const int r0 = tid >> 3, cq = (tid & 7) * 16;
#pragma unroll
  for (int j = 0; j < 2; ++j) {
    bf16x8 v = *(const bf16x8*)(Rt + r0 * RT_LD + cq + j * 8);
    *(bf16x8*)(x + (long)(b * NQ + qB + r0) * DD + dB + cq + j * 8) = v;
  }
}

extern "C" void kernel_launch(void* const* d_in, const int* in_sizes, int n_in,
                              void* d_out, int out_size, void* d_ws, size_t ws_size,
                              hipStream_t stream) {
  const float* proto = (const float*)d_in[0];
  const float* qx    = (const float*)d_in[1];
  const void*  mask  = d_in[2];
  const float* Wq    = (const float*)d_in[3];
  const float* Wk    = (const float*)d_in[4];
  const float* Wv    = (const float*)d_in[5];
  const float* Wproj = (const float*)d_in[6];
  float* out = (float*)d_out;

  char* w = (char*)d_ws;
  int*   flag  = (int*)w;
  int*   cnt   = (int*)(w + 64);
  int*   kpadA = (int*)(w + 128);
  float* denom = (float*)(w + 4096);
  size_t off = 65536;
  bf16* Wq_b  = (bf16*)(w + off); off += (size_t)DD * DD * 2;
  bf16* Wkv_b = (bf16*)(w + off); off += (size_t)DD * DD * 4;
  bf16* Wp_b  = (bf16*)(w + off); off += (size_t)DD * DD * 2;
  int*  idx   = (int*)(w + off);  off += (size_t)NB * NKV * 4;
  bf16* q_b   = (bf16*)(w + off); off += (size_t)NB * NQ * DD * 2;   // 8MB
  bf16* k_b   = (bf16*)(w + off); off += (size_t)NB * NKV * DD * 2;  // 32MB
  bf16* vT_b  = (bf16*)(w + off); off += (size_t)NB * NKV * DD * 2;  // 32MB
  bf16* x_b   = (bf16*)(w + off); off += (size_t)NB * NQ * DD * 2;   // 8MB
  size_t off_pp = off;
  bf16* proto_b = (bf16*)(w + off); off += (size_t)NB * NQ * DD * 2;
  bf16* qc_b    = (bf16*)(w + off);
  bf16* P       = (bf16*)(w + off_pp);   // 64MB, overlays proto/qc (dead by S)

  sniff_zero<<<1, 256, 0, stream>>>((const unsigned*)mask, flag, denom);
  scan_mask<<<8, 256, 0, stream>>>(mask, flag, idx, cnt, kpadA);

  cvt_kernel<<<NB * NQ * DD / 4 / 256, 256, 0, stream>>>(proto, proto_b, NB * NQ * DD / 4);
  gather_qx<<<dim3(NKV / 16, NB), 256, 0, stream>>>(qx, idx, cnt, qc_b);
  cvt_weights<<<4 * 65536 / 256, 256, 0, stream>>>(Wq, Wk, Wv, Wproj, Wq_b, Wkv_b, Wp_b);

  const float scale = 0.04419417382415922f;  // 512^-0.5

  // q = proto @ Wq^T
  gemm_n64<0><<<dim3(8, 64, 1), 256, 0, stream>>>(proto_b, Wq_b, q_b);
  // k | vT = qc @ [Wk;Wv]^T  compacted rows
  gemm_bt<5><<<dim3(256, 8, 1), 256, 0, stream>>>(
      qc_b, Wkv_b, k_b, vT_b, 1024, DD, DD, 0L, 0L, 0L,
      cnt, kpadA, nullptr, 0.f, 0);
  // P = exp(scale * q @ k^T), zero cols >= cnt[b]; denom += row sums
  gemm_bt<2><<<dim3(NKV / 128, NQ / 128, NB), 256, 0, stream>>>(
      q_b, k_b, P, nullptr, NKV, DD, DD,
      (long)NQ * DD, (long)NKV * DD, (long)NQ * NKV,
      cnt, kpadA, denom, scale, NQ);
  // x = (P @ vT^T) / denom
  pv_direct<<<dim3(32, 4, 8), 256, 0, stream>>>(P, vT_b, denom, kpadA, x_b);
  // out = x @ Wproj^T  fp32
  gemm_n64<4><<<dim3(8, 64, 1), 256, 0, stream>>>(x_b, Wp_b, out);
}

// Round 8
// 324.712 us; speedup vs baseline: 1.0897x; 1.0897x over previous
//
#include <hip/hip_runtime.h>
#include <hip/hip_bf16.h>
#include <stdint.h>

// QSCrossAttention: B=8, Nq=1024, Nkv=4096, D=512, fp32 I/O, bf16 MFMA compute.
// R8: R6 config (best measured: 342us) + register-prefetch double-buffered
//     K-loops. R7 proved occupancy wasn't the limiter (halved LDS, same 18%
//     occ, dur worse) -> hide HBM latency WITHIN the wave: global->VGPR
//     prefetch of tile t+1 overlaps MFMA+ds_read of tile t.

typedef __bf16 bf16;
typedef bf16 bf16x8 __attribute__((ext_vector_type(8)));
typedef bf16 bf16x4 __attribute__((ext_vector_type(4)));
typedef float f32x4 __attribute__((ext_vector_type(4)));
typedef int4 i4;

#define NB 8
#define NQ 1024
#define NKV 4096
#define DD 512
#define RT_LD 136  // repack leading dim for 128-col tiles (272B rows)

__global__ void cvt_kernel(const float* __restrict__ src, bf16* __restrict__ dst, int n4) {
  int i = blockIdx.x * blockDim.x + threadIdx.x;
  if (i < n4) {
    float4 v = ((const float4*)src)[i];
    bf16x4 o;
    o.x = (bf16)v.x; o.y = (bf16)v.y; o.z = (bf16)v.z; o.w = (bf16)v.w;
    ((bf16x4*)dst)[i] = o;
  }
}

__global__ void cvt_weights(const float* __restrict__ Wq, const float* __restrict__ Wk,
                            const float* __restrict__ Wv, const float* __restrict__ Wp,
                            bf16* __restrict__ Wq_b, bf16* __restrict__ Wkv_b,
                            bf16* __restrict__ Wp_b) {
  int i = blockIdx.x * blockDim.x + threadIdx.x;
  int w = i >> 16, r = i & 65535;
  const float* src = (w == 0) ? Wq : (w == 1) ? Wk : (w == 2) ? Wv : Wp;
  bf16x4* dst = (w == 0) ? (bf16x4*)Wq_b
              : (w == 3) ? (bf16x4*)Wp_b
                         : (bf16x4*)Wkv_b + (w == 2 ? 65536 : 0);
  float4 v = ((const float4*)src)[r];
  bf16x4 o;
  o.x = (bf16)v.x; o.y = (bf16)v.y; o.z = (bf16)v.z; o.w = (bf16)v.w;
  dst[r] = o;
}

// Sniff mask dtype (0:int32 1:f32 2:bytes) + zero denominators.
__global__ void sniff_zero(const unsigned* __restrict__ mask, int* __restrict__ flag,
                           float* __restrict__ denom) {
  __shared__ int s_bad0, s_bad1;
  if (threadIdx.x == 0) { s_bad0 = 0; s_bad1 = 0; }
  __syncthreads();
  int b0 = 0, b1 = 0;
  for (int i = threadIdx.x; i < 8192; i += 256) {
    unsigned v = mask[i];
    if (v > 1u) b0 = 1;
    if (v != 0u && v != 0x3F800000u) b1 = 1;
  }
  if (b0) atomicOr(&s_bad0, 1);
  if (b1) atomicOr(&s_bad1, 1);
  for (int i = threadIdx.x; i < NB * NQ; i += 256) denom[i] = 0.f;
  __syncthreads();
  if (threadIdx.x == 0) *flag = (s_bad0 == 0) ? 0 : ((s_bad1 == 0) ? 1 : 2);
}

// Per-batch prefix scan of mask -> compacted kept-index list, cnt, kpad.
__global__ void scan_mask(const void* __restrict__ mask, const int* __restrict__ flagP,
                          int* __restrict__ idx, int* __restrict__ cnt,
                          int* __restrict__ kpad) {
  const int b = blockIdx.x, tid = threadIdx.x;
  const int mode = *flagP;
  __shared__ int ps[256];
  unsigned bits = 0;
  int c = 0;
  const int base = tid * 16;
  for (int i = 0; i < 16; ++i) {
    const int col = base + i;
    bool k;
    if (mode == 0)      k = ((const int*)mask)[b * NKV + col] != 0;
    else if (mode == 1) k = ((const float*)mask)[b * NKV + col] != 0.f;
    else                k = ((const unsigned char*)mask)[b * NKV + col] != 0;
    bits |= (unsigned)k << i;
    c += k;
  }
  ps[tid] = c;
  __syncthreads();
  for (int s = 1; s < 256; s <<= 1) {
    int v = (tid >= s) ? ps[tid - s] : 0;
    __syncthreads();
    ps[tid] += v;
    __syncthreads();
  }
  int off = ps[tid] - c;
  for (int i = 0; i < 16; ++i)
    if ((bits >> i) & 1) idx[b * NKV + off++] = base + i;
  if (tid == 255) {
    cnt[b] = ps[255];
    kpad[b] = (ps[255] + 127) & ~127;
  }
}

// qc[b][r] = bf16(qx[b][idx[b][r]]) for r < cnt[b].
__global__ void gather_qx(const float* __restrict__ qx, const int* __restrict__ idx,
                          const int* __restrict__ cnt, bf16* __restrict__ qc) {
  const int b = blockIdx.y;
  const int wave = threadIdx.x >> 6, lane = threadIdx.x & 63;
  const int r0 = blockIdx.x * 16 + wave * 4;
  const int n = cnt[b];
#pragma unroll
  for (int j = 0; j < 4; ++j) {
    const int row = r0 + j;
    if (row >= n) return;
    const int src = idx[b * NKV + row];
    const float4* s = (const float4*)(qx + ((long)b * NKV + src) * DD) + lane;
    bf16x4* d = (bf16x4*)(qc + ((long)b * NKV + row) * DD) + lane;
    float4 v0 = s[0], v1 = s[64];
    bf16x4 o0, o1;
    o0.x = (bf16)v0.x; o0.y = (bf16)v0.y; o0.z = (bf16)v0.z; o0.w = (bf16)v0.w;
    o1.x = (bf16)v1.x; o1.y = (bf16)v1.y; o1.z = (bf16)v1.z; o1.w = (bf16)v1.w;
    d[0] = o0;
    d[64] = o1;
  }
}

// ---------------- 128x128-tile GEMM (S and kv projections) -----------------
// Register-prefetch K-loop: tile t+1 global->VGPR while MFMA of tile t runs.
// EPI 2 = S: exp + col<cnt zeroing + rowsum + P store.
// EPI 5 = kv dual (k row-major | vT transposed).
template <int EPI>
__global__ void __launch_bounds__(256, 2)
gemm_bt(const bf16* __restrict__ A, const bf16* __restrict__ Bw,
        void* __restrict__ Cp, void* __restrict__ Cp2,
        int N, int Klen, int Kstride,
        long sA, long sB, long sC,
        const int* __restrict__ cnt, const int* __restrict__ kpad,
        float* __restrict__ denom, float scale, int M) {
  __shared__ alignas(16) bf16 Smem[128 * RT_LD];
  bf16* As = Smem;
  bf16* Bs = Smem + 4096;
  bf16* Rt = Smem;
  const int tid = threadIdx.x;
  const int wave = tid >> 6, lane = tid & 63;
  const int l15 = lane & 15, l4 = lane >> 4;
  const int wm = (wave >> 1) * 64, wn = (wave & 1) * 64;
  const int bx = (EPI == 5) ? blockIdx.y : blockIdx.x;
  const int by = (EPI == 5) ? blockIdx.x : blockIdx.y;
  const int b = blockIdx.z;

  if constexpr (EPI == 2) {
    if (bx * 128 >= kpad[b]) return;
  } else {
    const int bb = by >> 5, loc = (by & 31) * 128;
    if (loc >= kpad[bb]) return;
  }

  const bf16* Ab = A + (long)b * sA + (long)(by * 128) * Kstride;
  const bf16* Bb = Bw + (long)b * sB + (long)(bx * 128) * Kstride;

  const int c0 = wave * 2, c1 = wave * 2 + 1;
  const int srow = lane >> 2;
  const int scol = (lane & 3) * 8;
  const bf16* ag0 = Ab + (long)(c0 * 16 + srow) * Kstride + scol;
  const bf16* ag1 = Ab + (long)(c1 * 16 + srow) * Kstride + scol;
  const bf16* bg0 = Bb + (long)(c0 * 16 + srow) * Kstride + scol;
  const bf16* bg1 = Bb + (long)(c1 * 16 + srow) * Kstride + scol;
  bf16* al0 = As + c0 * 512 + lane * 8;
  bf16* al1 = As + c1 * 512 + lane * 8;
  bf16* bl0 = Bs + c0 * 512 + lane * 8;
  bf16* bl1 = Bs + c1 * 512 + lane * 8;

  f32x4 acc[4][4] = {};

  // prologue: tile 0 into registers
  i4 ra0 = *(const i4*)ag0, ra1 = *(const i4*)ag1;
  i4 rb0 = *(const i4*)bg0, rb1 = *(const i4*)bg1;

  for (int kt = 0; kt < Klen; kt += 32) {
    __syncthreads();  // previous iteration's LDS readers done
    *(i4*)al0 = ra0;
    *(i4*)al1 = ra1;
    *(i4*)bl0 = rb0;
    *(i4*)bl1 = rb1;
    if (kt + 32 < Klen) {  // prefetch next tile (vmcnt waits at next ds_write)
      ag0 += 32; ag1 += 32; bg0 += 32; bg1 += 32;
      ra0 = *(const i4*)ag0; ra1 = *(const i4*)ag1;
      rb0 = *(const i4*)bg0; rb1 = *(const i4*)bg1;
    }
    __syncthreads();  // ds_writes visible
    bf16x8 af[4], bfr[4];
#pragma unroll
    for (int t = 0; t < 4; ++t)
      af[t] = *(const bf16x8*)(As + (wm + t * 16 + l15) * 32 + l4 * 8);
#pragma unroll
    for (int t = 0; t < 4; ++t)
      bfr[t] = *(const bf16x8*)(Bs + (wn + t * 16 + l15) * 32 + l4 * 8);
#pragma unroll
    for (int mt = 0; mt < 4; ++mt)
#pragma unroll
      for (int nt = 0; nt < 4; ++nt)
        acc[mt][nt] = __builtin_amdgcn_mfma_f32_16x16x32_bf16(af[mt], bfr[nt],
                                                              acc[mt][nt], 0, 0, 0);
  }

  const int rowBase = by * 128 + wm;
  const int colBase = bx * 128 + wn;
  const int tR = by * 128;
  const int tC = bx * 128;

  __syncthreads();  // K-loop LDS dead before Rt overlay

  if constexpr (EPI == 2) {
    bf16* C = (bf16*)Cp + (long)b * sC;
    const int nkeep = cnt[b];
    float rs[4][4];
#pragma unroll
    for (int mt = 0; mt < 4; ++mt)
#pragma unroll
      for (int r = 0; r < 4; ++r) rs[mt][r] = 0.f;
#pragma unroll
    for (int nt = 0; nt < 4; ++nt) {
      const bool keep = (colBase + nt * 16 + l15) < nkeep;
#pragma unroll
      for (int mt = 0; mt < 4; ++mt)
#pragma unroll
        for (int r = 0; r < 4; ++r) {
          float p = keep ? __expf(acc[mt][nt][r] * scale) : 0.f;
          rs[mt][r] += p;
          Rt[(wm + mt * 16 + l4 * 4 + r) * RT_LD + wn + nt * 16 + l15] = (bf16)p;
        }
    }
#pragma unroll
    for (int mt = 0; mt < 4; ++mt)
#pragma unroll
      for (int r = 0; r < 4; ++r) {
        float v = rs[mt][r];
        v += __shfl_xor(v, 1, 64);
        v += __shfl_xor(v, 2, 64);
        v += __shfl_xor(v, 4, 64);
        v += __shfl_xor(v, 8, 64);
        if (l15 == 0)
          atomicAdd(&denom[b * M + rowBase + mt * 16 + l4 * 4 + r], v);
      }
    __syncthreads();
    const int r0 = tid >> 2, cq = (tid & 3) * 32;
#pragma unroll
    for (int h = 0; h < 128; h += 64)
#pragma unroll
      for (int j = 0; j < 4; ++j) {
        bf16x8 v = *(const bf16x8*)(Rt + (r0 + h) * RT_LD + cq + j * 8);
        *(bf16x8*)(C + (long)(tR + r0 + h) * N + tC + cq + j * 8) = v;
      }
  } else {  // EPI == 5: kv dual epilogue, rows flat over compacted [B][...]
    if (tC < 512) {
      bf16* C = (bf16*)Cp;  // k: [B*NKV][512]
#pragma unroll
      for (int mt = 0; mt < 4; ++mt)
#pragma unroll
        for (int nt = 0; nt < 4; ++nt)
#pragma unroll
          for (int r = 0; r < 4; ++r)
            Rt[(wm + mt * 16 + l4 * 4 + r) * RT_LD + wn + nt * 16 + l15] =
                (bf16)acc[mt][nt][r];
      __syncthreads();
      const int r0 = tid >> 2, cq = (tid & 3) * 32;
#pragma unroll
      for (int h = 0; h < 128; h += 64)
#pragma unroll
        for (int j = 0; j < 4; ++j) {
          bf16x8 v = *(const bf16x8*)(Rt + (r0 + h) * RT_LD + cq + j * 8);
          *(bf16x8*)(C + (long)(tR + r0 + h) * 512 + tC + cq + j * 8) = v;
        }
    } else {
      bf16* C = (bf16*)Cp2;  // vT: [B][512][NKV], transpose via Rt[d][kv]
#pragma unroll
      for (int mt = 0; mt < 4; ++mt) {
        const int r0 = wm + mt * 16 + l4 * 4;
#pragma unroll
        for (int nt = 0; nt < 4; ++nt) {
          const int cloc = wn + nt * 16 + l15;
          bf16x4 o;
          o.x = (bf16)acc[mt][nt][0]; o.y = (bf16)acc[mt][nt][1];
          o.z = (bf16)acc[mt][nt][2]; o.w = (bf16)acc[mt][nt][3];
          *(bf16x4*)(Rt + cloc * RT_LD + r0) = o;
        }
      }
      __syncthreads();
      const int bb = tR >> 12, kvloc = tR & 4095;
      const int d0 = tid >> 2, kvq = (tid & 3) * 32;
#pragma unroll
      for (int h = 0; h < 128; h += 64)
#pragma unroll
        for (int j = 0; j < 4; ++j) {
          bf16x8 v = *(const bf16x8*)(Rt + (d0 + h) * RT_LD + kvq + j * 8);
          *(bf16x8*)(C + (long)bb * DD * NKV + (long)(tC - 512 + d0 + h) * NKV +
                     kvloc + kvq + j * 8) = v;
        }
    }
  }
}

// ---------------- 128x64-tile GEMM (q-proj, out-proj) ----------------------
template <int EPI>
__global__ void __launch_bounds__(256, 4)
gemm_n64(const bf16* __restrict__ A, const bf16* __restrict__ Bw,
         void* __restrict__ Cp) {
  constexpr int SME = (EPI == 0) ? 128 * 72 : 6144;
  __shared__ alignas(16) bf16 Smem[SME];
  bf16* As = Smem;
  bf16* Bs = Smem + 4096;
  bf16* Rt = Smem;
  const int tid = threadIdx.x;
  const int wave = tid >> 6, lane = tid & 63;
  const int l15 = lane & 15, l4 = lane >> 4;
  const int wm = (wave >> 1) * 64, wn = (wave & 1) * 32;

  const bf16* Ab = A + (long)(blockIdx.y * 128) * DD;
  const bf16* Bb = Bw + (long)(blockIdx.x * 64) * DD;

  const int srow = lane >> 2, scol = (lane & 3) * 8;
  const bf16* ag0 = Ab + (long)(wave * 32 + srow) * DD + scol;
  const bf16* ag1 = ag0 + 16 * DD;
  const bf16* bg0 = Bb + (long)(wave * 16 + srow) * DD + scol;
  bf16* al0 = As + wave * 1024 + lane * 8;
  bf16* al1 = al0 + 512;
  bf16* bl0 = Bs + wave * 512 + lane * 8;

  f32x4 acc[4][2] = {};

  i4 ra0 = *(const i4*)ag0, ra1 = *(const i4*)ag1, rb0 = *(const i4*)bg0;

  for (int kt = 0; kt < DD; kt += 32) {
    __syncthreads();
    *(i4*)al0 = ra0;
    *(i4*)al1 = ra1;
    *(i4*)bl0 = rb0;
    if (kt + 32 < DD) {
      ag0 += 32; ag1 += 32; bg0 += 32;
      ra0 = *(const i4*)ag0; ra1 = *(const i4*)ag1; rb0 = *(const i4*)bg0;
    }
    __syncthreads();
    bf16x8 af[4], bfr[2];
#pragma unroll
    for (int t = 0; t < 4; ++t)
      af[t] = *(const bf16x8*)(As + (wm + t * 16 + l15) * 32 + l4 * 8);
#pragma unroll
    for (int t = 0; t < 2; ++t)
      bfr[t] = *(const bf16x8*)(Bs + (wn + t * 16 + l15) * 32 + l4 * 8);
#pragma unroll
    for (int mt = 0; mt < 4; ++mt)
#pragma unroll
      for (int nt = 0; nt < 2; ++nt)
        acc[mt][nt] = __builtin_amdgcn_mfma_f32_16x16x32_bf16(af[mt], bfr[nt],
                                                              acc[mt][nt], 0, 0, 0);
  }

  const int tR = blockIdx.y * 128, tC = blockIdx.x * 64;
  if constexpr (EPI == 0) {
    __syncthreads();
#pragma unroll
    for (int mt = 0; mt < 4; ++mt)
#pragma unroll
      for (int nt = 0; nt < 2; ++nt)
#pragma unroll
        for (int r = 0; r < 4; ++r)
          Rt[(wm + mt * 16 + l4 * 4 + r) * 72 + wn + nt * 16 + l15] =
              (bf16)acc[mt][nt][r];
    __syncthreads();
    bf16* C = (bf16*)Cp;
    const int r0 = tid >> 1, cq = (tid & 1) * 32;
#pragma unroll
    for (int j = 0; j < 4; ++j) {
      bf16x8 v = *(const bf16x8*)(Rt + r0 * 72 + cq + j * 8);
      *(bf16x8*)(C + (long)(tR + r0) * DD + tC + cq + j * 8) = v;
    }
  } else {
    float* C = (float*)Cp;
#pragma unroll
    for (int mt = 0; mt < 4; ++mt)
#pragma unroll
      for (int nt = 0; nt < 2; ++nt)
#pragma unroll
        for (int r = 0; r < 4; ++r)
          C[(long)(tR + wm + mt * 16 + l4 * 4 + r) * DD + tC + wn + nt * 16 + l15] =
              acc[mt][nt][r];
  }
}

// ---------------- PV direct: x = (P @ vT^T) / denom ------------------------
// Tile 64q x 128d, K = kpad[b] (compacted). Grid (16,4,8). Reg-prefetch loop.
__global__ void __launch_bounds__(256, 4)
pv_direct(const bf16* __restrict__ P, const bf16* __restrict__ vT,
          const float* __restrict__ denom, const int* __restrict__ kpad,
          bf16* __restrict__ x) {
  __shared__ alignas(16) bf16 Smem[64 * RT_LD];
  bf16* As = Smem;
  bf16* Bs = Smem + 2048;
  bf16* Rt = Smem;
  const int tid = threadIdx.x;
  const int wave = tid >> 6, lane = tid & 63;
  const int l15 = lane & 15, l4 = lane >> 4;
  const int wm = (wave >> 1) * 32, wn = (wave & 1) * 64;
  const int qB = blockIdx.x * 64;
  const int dB = blockIdx.y * 128;
  const int b = blockIdx.z;
  const int Kb = kpad[b];

  const bf16* Ab = P + (long)b * NQ * NKV + (long)qB * NKV;
  const bf16* Bb = vT + (long)b * DD * NKV + (long)dB * NKV;

  const int srow = lane >> 2, scol = (lane & 3) * 8;
  const bf16* ag = Ab + (long)(wave * 16 + srow) * NKV + scol;
  const bf16* bg0 = Bb + (long)(wave * 32 + srow) * NKV + scol;
  const bf16* bg1 = bg0 + 16 * NKV;
  bf16* al = As + wave * 512 + lane * 8;
  bf16* bl0 = Bs + wave * 1024 + lane * 8;
  bf16* bl1 = bl0 + 512;

  f32x4 acc[2][4] = {};

  i4 ra = *(const i4*)ag, rb0 = *(const i4*)bg0, rb1 = *(const i4*)bg1;

  for (int kt = 0; kt < Kb; kt += 32) {
    __syncthreads();
    *(i4*)al = ra;
    *(i4*)bl0 = rb0;
    *(i4*)bl1 = rb1;
    if (kt + 32 < Kb) {
      ag += 32; bg0 += 32; bg1 += 32;
      ra = *(const i4*)ag; rb0 = *(const i4*)bg0; rb1 = *(const i4*)bg1;
    }
    __syncthreads();
    bf16x8 af[2], bfr[4];
#pragma unroll
    for (int t = 0; t < 2; ++t)
      af[t] = *(const bf16x8*)(As + (wm + t * 16 + l15) * 32 + l4 * 8);
#pragma unroll
    for (int t = 0; t < 4; ++t)
      bfr[t] = *(const bf16x8*)(Bs + (wn + t * 16 + l15) * 32 + l4 * 8);
#pragma unroll
    for (int mt = 0; mt < 2; ++mt)
#pragma unroll
      for (int nt = 0; nt < 4; ++nt)
        acc[mt][nt] = __builtin_amdgcn_mfma_f32_16x16x32_bf16(af[mt], bfr[nt],
                                                              acc[mt][nt], 0, 0, 0);
  }

  __syncthreads();
#pragma unroll
  for (int mt = 0; mt < 2; ++mt)
#pragma unroll
    for (int r = 0; r < 4; ++r) {
      const int row = wm + mt * 16 + l4 * 4 + r;
      const float inv = 1.0f / denom[b * NQ + qB + row];
#pragma unroll
      for (int nt = 0; nt < 4; ++nt)
        Rt[row * RT_LD + wn + nt * 16 + l15] = (bf16)(acc[mt][nt][r] * inv);
    }
  __syncthreads();
  const int r0 = tid >> 2, cq = (tid & 3) * 32;
#pragma unroll
  for (int j = 0; j < 4; ++j) {
    bf16x8 v = *(const bf16x8*)(Rt + r0 * RT_LD + cq + j * 8);
    *(bf16x8*)(x + (long)(b * NQ + qB + r0) * DD + dB + cq + j * 8) = v;
  }
}

extern "C" void kernel_launch(void* const* d_in, const int* in_sizes, int n_in,
                              void* d_out, int out_size, void* d_ws, size_t ws_size,
                              hipStream_t stream) {
  const float* proto = (const float*)d_in[0];
  const float* qx    = (const float*)d_in[1];
  const void*  mask  = d_in[2];
  const float* Wq    = (const float*)d_in[3];
  const float* Wk    = (const float*)d_in[4];
  const float* Wv    = (const float*)d_in[5];
  const float* Wproj = (const float*)d_in[6];
  float* out = (float*)d_out;

  char* w = (char*)d_ws;
  int*   flag  = (int*)w;
  int*   cnt   = (int*)(w + 64);
  int*   kpadA = (int*)(w + 128);
  float* denom = (float*)(w + 4096);
  size_t off = 65536;
  bf16* Wq_b  = (bf16*)(w + off); off += (size_t)DD * DD * 2;
  bf16* Wkv_b = (bf16*)(w + off); off += (size_t)DD * DD * 4;
  bf16* Wp_b  = (bf16*)(w + off); off += (size_t)DD * DD * 2;
  int*  idx   = (int*)(w + off);  off += (size_t)NB * NKV * 4;
  bf16* q_b   = (bf16*)(w + off); off += (size_t)NB * NQ * DD * 2;   // 8MB
  bf16* k_b   = (bf16*)(w + off); off += (size_t)NB * NKV * DD * 2;  // 32MB
  bf16* vT_b  = (bf16*)(w + off); off += (size_t)NB * NKV * DD * 2;  // 32MB
  bf16* x_b   = (bf16*)(w + off); off += (size_t)NB * NQ * DD * 2;   // 8MB
  size_t off_pp = off;
  bf16* proto_b = (bf16*)(w + off); off += (size_t)NB * NQ * DD * 2;
  bf16* qc_b    = (bf16*)(w + off);
  bf16* P       = (bf16*)(w + off_pp);   // 64MB, overlays proto/qc (dead by S)

  sniff_zero<<<1, 256, 0, stream>>>((const unsigned*)mask, flag, denom);
  scan_mask<<<8, 256, 0, stream>>>(mask, flag, idx, cnt, kpadA);

  cvt_kernel<<<NB * NQ * DD / 4 / 256, 256, 0, stream>>>(proto, proto_b, NB * NQ * DD / 4);
  gather_qx<<<dim3(NKV / 16, NB), 256, 0, stream>>>(qx, idx, cnt, qc_b);
  cvt_weights<<<4 * 65536 / 256, 256, 0, stream>>>(Wq, Wk, Wv, Wproj, Wq_b, Wkv_b, Wp_b);

  const float scale = 0.04419417382415922f;  // 512^-0.5

  // q = proto @ Wq^T
  gemm_n64<0><<<dim3(8, 64, 1), 256, 0, stream>>>(proto_b, Wq_b, q_b);
  // k | vT = qc @ [Wk;Wv]^T  compacted rows
  gemm_bt<5><<<dim3(256, 8, 1), 256, 0, stream>>>(
      qc_b, Wkv_b, k_b, vT_b, 1024, DD, DD, 0L, 0L, 0L,
      cnt, kpadA, nullptr, 0.f, 0);
  // P = exp(scale * q @ k^T), zero cols >= cnt[b]; denom += row sums
  gemm_bt<2><<<dim3(NKV / 128, NQ / 128, NB), 256, 0, stream>>>(
      q_b, k_b, P, nullptr, NKV, DD, DD,
      (long)NQ * DD, (long)NKV * DD, (long)NQ * NKV,
      cnt, kpadA, denom, scale, NQ);
  // x = (P @ vT^T) / denom
  pv_direct<<<dim3(16, 4, 8), 256, 0, stream>>>(P, vT_b, denom, kpadA, x_b);
  // out = x @ Wproj^T  fp32
  gemm_n64<4><<<dim3(8, 64, 1), 256, 0, stream>>>(x_b, Wp_b, out);
}